// Round 3
// baseline (55.903 us; speedup 1.0000x reference)
//
#include <hip/hip_runtime.h>
#include <stdint.h>

#define ROWS 8192     // B*N
#define D    128
#define CSPLIT 16
#define CPS  (ROWS / CSPLIT)    // 512 cols per split
#define BM   256
#define BN   64
#define NT   (CPS / BN)         // 8 col tiles per split
#define SQRT_LOG2E 1.2011224087864498f

typedef __bf16 bf16x8 __attribute__((ext_vector_type(8)));
typedef float  f32x4  __attribute__((ext_vector_type(4)));

typedef const __attribute__((address_space(1))) uint32_t guint;
typedef __attribute__((address_space(3))) uint32_t luint;

__device__ __forceinline__ void gload_lds16(const void* g, void* l) {
    __builtin_amdgcn_global_load_lds((guint*)g, (luint*)l, 16, 0, 0);
}

__device__ __forceinline__ ushort f2bf(float f) {
    union { float f; uint32_t u; } x; x.f = f;
    uint32_t r = x.u + 0x7FFFu + ((x.u >> 16) & 1u);
    return (ushort)(r >> 16);
}

// ---- Kernel 1: L2-normalize rows, cast to bf16. fk rows additionally
// scaled by sqrt(log2e) so the k-Gram comes out pre-multiplied by log2e
// (exp(logit) == exp2(sk), saving one v_mul per Gram element). ----
__global__ __launch_bounds__(256) void k_norm(
    const float* __restrict__ fk, const float* __restrict__ fq,
    ushort* __restrict__ fkn, ushort* __restrict__ fqn)
{
    int gw = (blockIdx.x * 256 + threadIdx.x) >> 6;   // one wave per row
    int l  = threadIdx.x & 63;
    const float* src; ushort* dst; int r; float scale;
    if (gw < ROWS) { src = fk; dst = fkn; r = gw; scale = SQRT_LOG2E; }
    else           { src = fq; dst = fqn; r = gw - ROWS; scale = 1.0f; }
    float2 v = *reinterpret_cast<const float2*>(&src[r * D + l * 2]);
    float ss = v.x * v.x + v.y * v.y;
    #pragma unroll
    for (int m = 1; m < 64; m <<= 1) ss += __shfl_xor(ss, m, 64);
    float inv = scale / fmaxf(sqrtf(ss), 1e-12f);
    ushort2 o; o.x = f2bf(v.x * inv); o.y = f2bf(v.y * inv);
    *reinterpret_cast<ushort2*>(&dst[r * D + l * 2]) = o;
}

// ---- Kernel 2: fused Gram + exp + masked accumulation ----
// grid = (32 row-tiles, 16 col-splits) = 512 blocks (2/CU), block = 256
// (4 waves x 64 rows each => each LDS B-fragment read feeds 4 MFMAs)
__global__ __launch_bounds__(256, 2) void k_gram(
    const ushort* __restrict__ fkn, const ushort* __restrict__ fqn,
    float* __restrict__ pneg, float* __restrict__ ppos)
{
    __shared__ ushort lds[2][2 * BN * D];   // 2 bufs x (fk 16KB + fq 16KB) = 64 KiB
    const int rt = blockIdx.x;
    const int cs = blockIdx.y;
    const int w  = threadIdx.x >> 6;        // 0..3
    const int l  = threadIdx.x & 63;
    const int lrow = l >> 4, lcol = l & 15;
    const int r0 = rt * BM;

    // Pre-swizzled per-lane SOURCE byte offsets (rule #21): gload_lds writes
    // LDS linearly; chunk L = t*256 + tid -> row=L>>4, slot=L&15, src col=slot^(row&7)
    int off[4];
    #pragma unroll
    for (int t = 0; t < 4; ++t) {
        int L = t * 256 + w * 64 + l;
        int row = L >> 4, slot = L & 15;
        int col = slot ^ (row & 7);
        off[t] = row * 256 + col * 16;
    }

    auto issue_stage = [&](int buf, int cbase) {
        const char* fkb = (const char*)fkn + (size_t)cbase * 256;
        const char* fqb = (const char*)fqn + (size_t)cbase * 256;
        #pragma unroll
        for (int t = 0; t < 4; ++t) {
            gload_lds16(fkb + off[t], &lds[buf][t * 2048 + w * 512]);
            gload_lds16(fqb + off[t], &lds[buf][BN * D + t * 2048 + w * 512]);
        }
    };

    issue_stage(0, cs * CPS);

    // A fragments (4 row-groups x 4 k-steps, both tensors), global->reg once.
    bf16x8 ak[4][4], aq[4][4];
    #pragma unroll
    for (int rg = 0; rg < 4; ++rg) {
        int arow = r0 + w * 64 + rg * 16 + lcol;      // A row: m = lane&15
        #pragma unroll
        for (int ks = 0; ks < 4; ++ks) {              // k = ks*32 + (lane>>4)*8 + e
            ak[rg][ks] = *reinterpret_cast<const bf16x8*>(fkn + arow * D + ks * 32 + lrow * 8);
            aq[rg][ks] = *reinterpret_cast<const bf16x8*>(fqn + arow * D + ks * 32 + lrow * 8);
        }
    }

    // wave's 64 rows are exactly one aligned i-block => diag tile wave-uniform
    const int diagc = r0 + w * 64;

    float accp[4][4] = {};
    float accn[4][4] = {};

    __syncthreads();

    int cur = 0;
    for (int t = 0; t < NT; ++t) {
        const int cbase = cs * CPS + t * BN;
        if (t + 1 < NT) issue_stage(cur ^ 1, cbase + BN);   // async prefetch
        const bool diag = (cbase == diagc);                 // wave-uniform
        const ushort* bkb = &lds[cur][0];
        const ushort* bqb = &lds[cur][BN * D];
        #pragma unroll
        for (int cc = 0; cc < 4; ++cc) {
            int brow = cc * 16 + lcol;                      // B row: n = lane&15
            f32x4 sk[4] = {{0,0,0,0},{0,0,0,0},{0,0,0,0},{0,0,0,0}};
            f32x4 sq[4] = {{0,0,0,0},{0,0,0,0},{0,0,0,0},{0,0,0,0}};
            #pragma unroll
            for (int ks = 0; ks < 4; ++ks) {
                int slot = (ks * 4 + lrow) ^ (brow & 7);
                bf16x8 bk = *reinterpret_cast<const bf16x8*>(bkb + brow * D + slot * 8);
                bf16x8 bq = *reinterpret_cast<const bf16x8*>(bqb + brow * D + slot * 8);
                #pragma unroll
                for (int rg = 0; rg < 4; ++rg) {
                    sk[rg] = __builtin_amdgcn_mfma_f32_16x16x32_bf16(ak[rg][ks], bk, sk[rg], 0, 0, 0);
                    sq[rg] = __builtin_amdgcn_mfma_f32_16x16x32_bf16(aq[rg][ks], bq, sq[rg], 0, 0, 0);
                }
            }
            // C layout: row = (lane>>4)*4 + e, col = lane&15
            if (diag) {
                #pragma unroll
                for (int rg = 0; rg < 4; ++rg)
                    #pragma unroll
                    for (int e = 0; e < 4; ++e)
                        accp[rg][e] += __builtin_exp2f(sk[rg][e]);
            } else {
                #pragma unroll
                for (int rg = 0; rg < 4; ++rg)
                    #pragma unroll
                    for (int e = 0; e < 4; ++e)
                        accn[rg][e] += __builtin_exp2f(sk[rg][e]) * sq[rg][e];
            }
        }
        __syncthreads();   // next tile staged (vmcnt) + reads of cur done (lgkm)
        cur ^= 1;
    }

    // reduce across the 16 lanes sharing the same output rows
    #pragma unroll
    for (int m = 1; m <= 8; m <<= 1) {
        #pragma unroll
        for (int rg = 0; rg < 4; ++rg)
            #pragma unroll
            for (int e = 0; e < 4; ++e) {
                accp[rg][e] += __shfl_xor(accp[rg][e], m, 64);
                accn[rg][e] += __shfl_xor(accn[rg][e], m, 64);
            }
    }
    if (lcol == 0) {
        #pragma unroll
        for (int rg = 0; rg < 4; ++rg)
            #pragma unroll
            for (int e = 0; e < 4; ++e) {
                int gr = r0 + w * 64 + rg * 16 + lrow * 4 + e;
                ppos[cs * ROWS + gr] = accp[rg][e];
                pneg[cs * ROWS + gr] = accn[rg][e];
            }
    }
}

// ---- Kernel 3a: per-row loss, 32-block partial sums ----
__global__ __launch_bounds__(256) void k_loss1(
    const float* __restrict__ pneg, const float* __restrict__ ppos,
    float* __restrict__ bsum)
{
    int r = blockIdx.x * 256 + threadIdx.x;
    float pos = 0.f, neg = 0.f;
    #pragma unroll
    for (int p = 0; p < CSPLIT; ++p) { pos += ppos[p * ROWS + r]; neg += pneg[p * ROWS + r]; }
    float s = log1pf(neg / pos);
    #pragma unroll
    for (int m = 1; m < 64; m <<= 1) s += __shfl_xor(s, m, 64);
    __shared__ float red[4];
    if ((threadIdx.x & 63) == 0) red[threadIdx.x >> 6] = s;
    __syncthreads();
    if (threadIdx.x == 0) bsum[blockIdx.x] = red[0] + red[1] + red[2] + red[3];
}

// ---- Kernel 3b: final mean ----
__global__ void k_loss2(const float* __restrict__ bsum, float* __restrict__ out)
{
    int l = threadIdx.x;
    float s = (l < 32) ? bsum[l] : 0.f;
    #pragma unroll
    for (int m = 1; m < 64; m <<= 1) s += __shfl_xor(s, m, 64);
    if (l == 0) out[0] = s * (1.0f / ROWS);
}

extern "C" void kernel_launch(void* const* d_in, const int* in_sizes, int n_in,
                              void* d_out, int out_size, void* d_ws, size_t ws_size,
                              hipStream_t stream)
{
    const float* fk = (const float*)d_in[0];
    const float* fq = (const float*)d_in[1];
    ushort* fkn = (ushort*)d_ws;                        // 2 MB
    ushort* fqn = fkn + ROWS * D;                       // 2 MB
    float*  pneg = (float*)(fqn + ROWS * D);            // 512 KB
    float*  ppos = pneg + CSPLIT * ROWS;                // 512 KB
    float*  bsum = ppos + CSPLIT * ROWS;                // 128 B

    k_norm<<<(2 * ROWS) / 4, 256, 0, stream>>>(fk, fq, fkn, fqn);
    k_gram<<<dim3(ROWS / BM, CSPLIT), 256, 0, stream>>>(fkn, fqn, pneg, ppos);
    k_loss1<<<32, 256, 0, stream>>>(pneg, ppos, bsum);
    k_loss2<<<1, 64, 0, stream>>>(bsum, (float*)d_out);
}